// Round 2
// baseline (1142.960 us; speedup 1.0000x reference)
//
#include <hip/hip_runtime.h>

#define B_    1024
#define L_    200
#define M_    (B_ * L_)     // 204800
#define E_    128
#define C_    384
#define K_    384
#define OUT_  10000
#define NT_   (M_ / 32)     // 6400 tiles of 32 rows
#define FCG_  768           // persistent fc grid: 3 blocks/CU x 256 CU

typedef __attribute__((ext_vector_type(8))) short bf16x8;
typedef __attribute__((ext_vector_type(4))) float f32x4;
typedef unsigned short u16;

__device__ __forceinline__ u16 f2bf(float f) {
    union { float f; unsigned u; } v; v.f = f;
    unsigned u = v.u;
    unsigned r = (u + 0x7fffu + ((u >> 16) & 1u)) >> 16;  // RNE
    return (u16)r;
}
__device__ __forceinline__ float bf2f(u16 s) {
    union { unsigned u; float f; } v; v.u = ((unsigned)s) << 16; return v.f;
}

// LDS-visibility barrier WITHOUT vmcnt drain: keeps next-tile gathers in flight
// across the barrier (raw s_barrier; __syncthreads would drain vmcnt(0)).
#define WG_BARRIER() asm volatile("s_waitcnt lgkmcnt(0)\n\ts_barrier" ::: "memory")

// ---------------- convert f32 -> bf16 (vectorized) ----------------
__global__ void cvt_bf16_kernel(const float4* __restrict__ src,
                                ushort4* __restrict__ dst, int n4) {
    int i = blockIdx.x * 256 + threadIdx.x;
    if (i < n4) {
        float4 v = src[i];
        ushort4 o;
        o.x = f2bf(v.x); o.y = f2bf(v.y); o.z = f2bf(v.z); o.w = f2bf(v.w);
        dst[i] = o;
    }
}

// ---------------- fused gather + FC GEMM + tanh + score ----------------
// Persistent-block cross-tile pipeline with WAVE-COOPERATIVE coalesced gathers:
// wave w owns rows w*8..w*8+7 of the tile. One load instruction covers a row
// PAIR: lanes 0-31 -> row 2q, lanes 32-63 -> row 2q+1, lane reads 16B at
// (lane&31)*16 -> two contiguous 512B segments per issue (same HBM behavior
// as global_load_lds, but data lives in regs so it stays in flight across the
// previous tile's MFMA + epilogue).
//   iter t:  convert regs(tile t) -> bf16 LDS buf[p]
//            BARRIER(lgkm only)
//            MFMA K-loop on buf[p]            (wfc B-frags from L1/L2)
//            issue gathers(t+FCG_)            [after wfc loads]
//            load indices(t+2*FCG_)
//            tanh/score epilogue              [hides gather latency]
//            BARRIER(lgkm only); score write; p ^= 1
__global__ __launch_bounds__(256, 3)
void fc_kernel(const int* __restrict__ starts, const int* __restrict__ paths,
               const int* __restrict__ ends,
               const float* __restrict__ node_emb, const float* __restrict__ path_emb,
               const u16* __restrict__ wfc, const float* __restrict__ a_vec,
               u16* __restrict__ h_out, float* __restrict__ scores) {
    __shared__ u16 Ab[2][32 * 392];    // 2 x 25088 B bf16 ping-pong (stride 392 u16)
    __shared__ float scpart[4][32];

    const int tid  = threadIdx.x;
    const int lane = tid & 63;
    const int wave = tid >> 6;
    const int lrow = lane & 15;
    const int quad = lane >> 4;
    const int half = lane >> 5;    // row-pair selector
    const int l31  = lane & 31;    // 16B chunk within the 512B row

    // hoisted per-thread attention-vector loads (constant across tiles)
    float av[6];
    #pragma unroll
    for (int j = 0; j < 6; ++j) av[j] = a_vec[(wave * 6 + j) * 16 + lrow];

    const u16* bB = wfc + (wave * 96 + lrow) * 384 + quad * 8;

    int    idx[12];   // [s*4+q]: indices for NEXT tile; row = wave*8 + 2q + half
    float4 dat[12];   // in-flight gathers for NEXT tile (coalesced row pairs)

    int t = blockIdx.x;
    // ---- prologue: idx(t) -> gathers(t) -> idx(t+FCG_) ----
    {
        const int mb = t * 32 + wave * 8 + half;
        #pragma unroll
        for (int q = 0; q < 4; ++q) {
            idx[q]     = starts[mb + 2 * q];
            idx[4 + q] = paths [mb + 2 * q];
            idx[8 + q] = ends  [mb + 2 * q];
        }
    }
    #pragma unroll
    for (int q = 0; q < 4; ++q) {
        dat[q]     = *(const float4*)(node_emb + (long)idx[q]     * 128 + l31 * 4);
        dat[4 + q] = *(const float4*)(path_emb + (long)idx[4 + q] * 128 + l31 * 4);
        dat[8 + q] = *(const float4*)(node_emb + (long)idx[8 + q] * 128 + l31 * 4);
    }
    {
        const int tn = (t + FCG_ < NT_) ? (t + FCG_) : t;
        const int mb = tn * 32 + wave * 8 + half;
        #pragma unroll
        for (int q = 0; q < 4; ++q) {
            idx[q]     = starts[mb + 2 * q];
            idx[4 + q] = paths [mb + 2 * q];
            idx[8 + q] = ends  [mb + 2 * q];
        }
    }

    int p = 0;
    for (; t < NT_; t += FCG_) {
        u16* dst = Ab[p];

        // ---- A: convert in-flight row-pair gathers -> bf16 LDS ----
        // row = wave*8 + 2q + half; segment s at cols s*128 + l31*4 (u16 units).
        #pragma unroll
        for (int s = 0; s < 3; ++s) {
            #pragma unroll
            for (int q = 0; q < 4; ++q) {
                float4 v = dat[s * 4 + q];
                ushort4 o;
                o.x = f2bf(v.x); o.y = f2bf(v.y); o.z = f2bf(v.z); o.w = f2bf(v.w);
                const int row = wave * 8 + 2 * q + half;
                *(ushort4*)(dst + row * 392 + s * 128 + l31 * 4) = o;
            }
        }
        WG_BARRIER();   // ds_writes visible; vmcnt NOT drained

        // ---- D: MFMA K-loop (wfc from global, L1/L2-hot) ----
        const u16* aB0 = dst + lrow * 392 + quad * 8;
        const u16* aB1 = dst + (16 + lrow) * 392 + quad * 8;
        f32x4 acc[2][6];
        #pragma unroll
        for (int mt = 0; mt < 2; ++mt)
            #pragma unroll
            for (int j = 0; j < 6; ++j) acc[mt][j] = (f32x4){0.f, 0.f, 0.f, 0.f};

        for (int kk = 0; kk < 12; ++kk) {
            bf16x8 a0 = *(const bf16x8*)(aB0 + kk * 32);
            bf16x8 a1 = *(const bf16x8*)(aB1 + kk * 32);
            #pragma unroll
            for (int j = 0; j < 6; ++j) {
                bf16x8 bfr = *(const bf16x8*)(bB + j * (16 * 384) + kk * 32);
                acc[0][j] = __builtin_amdgcn_mfma_f32_16x16x32_bf16(a0, bfr, acc[0][j], 0, 0, 0);
                acc[1][j] = __builtin_amdgcn_mfma_f32_16x16x32_bf16(a1, bfr, acc[1][j], 0, 0, 0);
            }
        }
        __builtin_amdgcn_sched_barrier(0);   // pin: gathers issue AFTER wfc loads

        // ---- B1: issue next-tile gathers (coalesced row pairs) ----
        #pragma unroll
        for (int q = 0; q < 4; ++q) {
            dat[q]     = *(const float4*)(node_emb + (long)idx[q]     * 128 + l31 * 4);
            dat[4 + q] = *(const float4*)(path_emb + (long)idx[4 + q] * 128 + l31 * 4);
            dat[8 + q] = *(const float4*)(node_emb + (long)idx[8 + q] * 128 + l31 * 4);
        }
        // ---- B2: index loads for tile t + 2*FCG_ ----
        {
            int tnn = t + 2 * FCG_;
            tnn = (tnn < NT_) ? tnn : t;    // clamp keeps loads valid
            const int mb = tnn * 32 + wave * 8 + half;
            #pragma unroll
            for (int q = 0; q < 4; ++q) {
                idx[q]     = starts[mb + 2 * q];
                idx[4 + q] = paths [mb + 2 * q];
                idx[8 + q] = ends  [mb + 2 * q];
            }
        }
        __builtin_amdgcn_sched_barrier(0);   // pin: epilogue issues after gathers

        // ---- EP: tanh, h store, score partials (hides gather latency) ----
        const int m0 = t * 32;
        float sc00 = 0.f, sc01 = 0.f, sc02 = 0.f, sc03 = 0.f;
        float sc10 = 0.f, sc11 = 0.f, sc12 = 0.f, sc13 = 0.f;
        #pragma unroll
        for (int j = 0; j < 6; ++j) {
            const int col = (wave * 6 + j) * 16 + lrow;
            const float avj = av[j];
            #pragma unroll
            for (int mt = 0; mt < 2; ++mt) {
                const int mrow = m0 + mt * 16 + quad * 4;
                #pragma unroll
                for (int rr = 0; rr < 4; ++rr) {
                    float pre = acc[mt][j][rr];
                    float e = __expf(2.0f * pre);
                    float hv = 1.0f - 2.0f / (e + 1.0f);
                    h_out[(long)(mrow + rr) * 384 + col] = f2bf(hv);
                    float hs = hv * avj;
                    if (mt == 0) {
                        if      (rr == 0) sc00 += hs; else if (rr == 1) sc01 += hs;
                        else if (rr == 2) sc02 += hs; else              sc03 += hs;
                    } else {
                        if      (rr == 0) sc10 += hs; else if (rr == 1) sc11 += hs;
                        else if (rr == 2) sc12 += hs; else              sc13 += hs;
                    }
                }
            }
        }
        #pragma unroll
        for (int off = 1; off < 16; off <<= 1) {
            sc00 += __shfl_xor(sc00, off); sc01 += __shfl_xor(sc01, off);
            sc02 += __shfl_xor(sc02, off); sc03 += __shfl_xor(sc03, off);
            sc10 += __shfl_xor(sc10, off); sc11 += __shfl_xor(sc11, off);
            sc12 += __shfl_xor(sc12, off); sc13 += __shfl_xor(sc13, off);
        }
        if (lrow == 0) {
            scpart[wave][quad * 4 + 0] = sc00;
            scpart[wave][quad * 4 + 1] = sc01;
            scpart[wave][quad * 4 + 2] = sc02;
            scpart[wave][quad * 4 + 3] = sc03;
            scpart[wave][16 + quad * 4 + 0] = sc10;
            scpart[wave][16 + quad * 4 + 1] = sc11;
            scpart[wave][16 + quad * 4 + 2] = sc12;
            scpart[wave][16 + quad * 4 + 3] = sc13;
        }
        WG_BARRIER();   // scpart visible; gathers still in flight
        if (tid < 32)
            scores[m0 + tid] = scpart[0][tid] + scpart[1][tid] + scpart[2][tid] + scpart[3][tid];
        p ^= 1;
    }
}

// ---------------- softmax over L=200 per batch row (1 wave/block) ----------------
__global__ void softmax_kernel(const float* __restrict__ scores, float* __restrict__ attn) {
    int b = blockIdx.x;
    int t = threadIdx.x;
    const float* s = scores + b * L_;
    float v0 = s[t];
    float v1 = s[t + 64];
    float v2 = s[t + 128];
    float v3 = (t < 8) ? s[t + 192] : -INFINITY;
    float mx = fmaxf(fmaxf(v0, v1), fmaxf(v2, v3));
    #pragma unroll
    for (int off = 1; off < 64; off <<= 1) mx = fmaxf(mx, __shfl_xor(mx, off));
    float e0 = __expf(v0 - mx), e1 = __expf(v1 - mx), e2 = __expf(v2 - mx);
    float e3 = (t < 8) ? __expf(v3 - mx) : 0.f;
    float sum = e0 + e1 + e2 + e3;
    #pragma unroll
    for (int off = 1; off < 64; off <<= 1) sum += __shfl_xor(sum, off);
    float inv = 1.f / sum;
    float* o = attn + b * L_;
    o[t] = e0 * inv; o[t + 64] = e1 * inv; o[t + 128] = e2 * inv;
    if (t < 8) o[t + 192] = e3 * inv;
}

// ---------------- code_vectors = sum_l attn * h (bf16x8 loads, 4-wave L split) ----
__global__ __launch_bounds__(256)
void codevec_kernel(const u16* __restrict__ h, const float* __restrict__ attn,
                    u16* __restrict__ cv) {
    __shared__ float part[4][384];
    const int b = blockIdx.x;
    const int tid = threadIdx.x, lane = tid & 63, wave = tid >> 6;
    float acc[8];
    #pragma unroll
    for (int e = 0; e < 8; ++e) acc[e] = 0.f;
    if (lane < 48) {
        const u16* hp = h + (long)b * (L_ * 384) + lane * 8;
        const float* ap = attn + b * L_;
        #pragma unroll 10
        for (int l = wave; l < L_; l += 4) {
            float w = ap[l];
            bf16x8 v = *(const bf16x8*)(hp + (long)l * 384);
            #pragma unroll
            for (int e = 0; e < 8; ++e) acc[e] += bf2f((u16)v[e]) * w;
        }
        #pragma unroll
        for (int e = 0; e < 8; ++e) part[wave][lane * 8 + e] = acc[e];
    }
    __syncthreads();
    for (int c = tid; c < 384; c += 256) {
        cv[b * 384 + c] = f2bf(part[0][c] + part[1][c] + part[2][c] + part[3][c]);
    }
}

// ---------------- out = cv @ W_out^T + b_out ----------------
__global__ __launch_bounds__(256, 4)
void out_gemm_kernel(const u16* __restrict__ cv, const u16* __restrict__ wout,
                     const float* __restrict__ b_out, float* __restrict__ out) {
    const int tid = threadIdx.x;
    const int lane = tid & 63, wave = tid >> 6;
    const int lrow = lane & 15, quad = lane >> 4;
    const int m0  = blockIdx.x * 64 + wave * 16;
    const int n0b = blockIdx.y * 128;

    f32x4 acc[8];
    #pragma unroll
    for (int i = 0; i < 8; ++i) acc[i] = (f32x4){0.f, 0.f, 0.f, 0.f};

    const u16* aB = cv + (m0 + lrow) * 384 + quad * 8;
    for (int kk = 0; kk < 12; ++kk) {
        bf16x8 af = *(const bf16x8*)(aB + kk * 32);
        #pragma unroll
        for (int t = 0; t < 8; ++t) {
            int n = n0b + t * 16 + lrow;
            n = (n < OUT_) ? n : (OUT_ - 1);
            bf16x8 bfr = *(const bf16x8*)(wout + (long)n * 384 + kk * 32 + quad * 8);
            acc[t] = __builtin_amdgcn_mfma_f32_16x16x32_bf16(af, bfr, acc[t], 0, 0, 0);
        }
    }
    const int mrow = m0 + quad * 4;
    #pragma unroll
    for (int t = 0; t < 8; ++t) {
        int n = n0b + t * 16 + lrow;
        if (n < OUT_) {
            float bias = b_out[n];
            #pragma unroll
            for (int r = 0; r < 4; ++r)
                out[(long)(mrow + r) * OUT_ + n] = acc[t][r] + bias;
        }
    }
}

extern "C" void kernel_launch(void* const* d_in, const int* in_sizes, int n_in,
                              void* d_out, int out_size, void* d_ws, size_t ws_size,
                              hipStream_t stream) {
    const int*   starts   = (const int*)d_in[0];
    const int*   paths    = (const int*)d_in[1];
    const int*   ends     = (const int*)d_in[2];
    const float* node_emb = (const float*)d_in[3];
    const float* path_emb = (const float*)d_in[4];
    const float* W_fc     = (const float*)d_in[5];
    const float* a_vec    = (const float*)d_in[6];
    const float* W_out    = (const float*)d_in[7];
    const float* b_out    = (const float*)d_in[8];
    float* out = (float*)d_out;

    char* ws = (char*)d_ws;
    u16*   h_bf16 = (u16*)ws;   ws += (size_t)M_ * 384 * 2;
    float* scores = (float*)ws; ws += (size_t)M_ * 4;
    float* attn   = (float*)ws; ws += (size_t)M_ * 4;
    u16*   wfc_b  = (u16*)ws;   ws += (size_t)C_ * K_ * 2;
    u16*   wout_b = (u16*)ws;   ws += (size_t)OUT_ * K_ * 2;
    u16*   cv_b   = (u16*)ws;   ws += (size_t)B_ * C_ * 2;

    cvt_bf16_kernel<<<(C_ * K_ / 4 + 255) / 256, 256, 0, stream>>>(
        (const float4*)W_fc, (ushort4*)wfc_b, C_ * K_ / 4);
    cvt_bf16_kernel<<<(OUT_ * K_ / 4 + 255) / 256, 256, 0, stream>>>(
        (const float4*)W_out, (ushort4*)wout_b, OUT_ * K_ / 4);
    fc_kernel<<<FCG_, 256, 0, stream>>>(
        starts, paths, ends, node_emb, path_emb, wfc_b, a_vec, h_bf16, scores);
    softmax_kernel<<<B_, 64, 0, stream>>>(scores, attn);
    codevec_kernel<<<B_, 256, 0, stream>>>(h_bf16, attn, cv_b);
    out_gemm_kernel<<<dim3(16, 79), 256, 0, stream>>>(cv_b, wout_b, b_out, out);
}

// Round 4
// 993.594 us; speedup vs baseline: 1.1503x; 1.1503x over previous
//
#include <hip/hip_runtime.h>

#define B_    1024
#define L_    200
#define M_    (B_ * L_)     // 204800
#define E_    128
#define C_    384
#define K_    384
#define OUT_  10000
#define NT_   (M_ / 32)     // 6400 tiles of 32 rows
#define FCW_  512           // persistent fc grid: 2 blocks/CU x 256 CU

typedef __attribute__((ext_vector_type(8))) short bf16x8;
typedef __attribute__((ext_vector_type(4))) float f32x4;
typedef unsigned short u16;

__device__ __forceinline__ u16 f2bf(float f) {
    union { float f; unsigned u; } v; v.f = f;
    unsigned u = v.u;
    unsigned r = (u + 0x7fffu + ((u >> 16) & 1u)) >> 16;  // RNE
    return (u16)r;
}
__device__ __forceinline__ float bf2f(u16 s) {
    union { unsigned u; float f; } v; v.u = ((unsigned)s) << 16; return v.f;
}

// async global->LDS: per-lane global src, wave-uniform LDS base + lane*size dest
#define GLD16(g, l) __builtin_amdgcn_global_load_lds((const __attribute__((address_space(1))) void*)(g), \
                        (__attribute__((address_space(3))) void*)(l), 16, 0, 0)
#define GLD4(g, l)  __builtin_amdgcn_global_load_lds((const __attribute__((address_space(1))) void*)(g), \
                        (__attribute__((address_space(3))) void*)(l), 4, 0, 0)

// LDS-visibility barrier WITHOUT vmcnt drain (HW-proven idiom: separate asm
// waitcnt + builtin s_barrier, per learn_hip 8-phase template). In-flight
// global_load_lds for the next tile survives the barrier.
#define WG_BARRIER() do { asm volatile("s_waitcnt lgkmcnt(0)" ::: "memory"); \
                          __builtin_amdgcn_s_barrier(); } while (0)
// Gate: wait own wave's global_load_lds writes, then fence the scheduler so
// following ds_reads can't hoist above (rule #18).
#define VM_GATE() do { asm volatile("s_waitcnt vmcnt(0)" ::: "memory"); \
                       __builtin_amdgcn_sched_barrier(0); } while (0)

// ---------------- convert f32 -> bf16 (vectorized) ----------------
__global__ void cvt_bf16_kernel(const float4* __restrict__ src,
                                ushort4* __restrict__ dst, int n4) {
    int i = blockIdx.x * 256 + threadIdx.x;
    if (i < n4) {
        float4 v = src[i];
        ushort4 o;
        o.x = f2bf(v.x); o.y = f2bf(v.y); o.z = f2bf(v.z); o.w = f2bf(v.w);
        dst[i] = o;
    }
}

// ---------------- fused gather + FC GEMM + tanh + score ----------------
// R0 memory structure (global_load_lds staging, identical addresses/stores,
// proven 160 MB fetch) + persistent cross-tile pipeline:
//   iter t:  VM_GATE          (GLD(t) landed -- issued a full iteration ago)
//            convert own 8 rows f32stage -> bf16 buf   (separate buffers)
//            WG_BARRIER       (lgkm only)
//            issue GLD(t+1) -> f32stage  +  load idx(t+2) into regs
//            MFMA K-loop (bf16 buf + wfc from L1/L2)
//            tanh/h-store/score epilogue  [GLD(t+1) flying underneath]
//            WG_BARRIER; score write
__global__ __launch_bounds__(256, 2)
void fc_kernel(const int* __restrict__ starts, const int* __restrict__ paths,
               const int* __restrict__ ends,
               const float* __restrict__ node_emb, const float* __restrict__ path_emb,
               const u16* __restrict__ wfc, const float* __restrict__ a_vec,
               u16* __restrict__ h_out, float* __restrict__ scores) {
    __shared__ float Af32[32 * 388];   // f32 gather stage (49,664 B)
    __shared__ u16  Ab16[32 * 392];    // bf16 MFMA operand (25,088 B)
    __shared__ float scpart[4][32];

    const int tid  = threadIdx.x;
    const int lane = tid & 63;
    const int wave = tid >> 6;
    const int lrow = lane & 15;
    const int quad = lane >> 4;
    const int half = lane >> 5;    // 0: start-seg (node), 1: path-seg
    const int l32  = lane & 31;

    // hoisted per-thread attention-vector loads (constant across tiles)
    float av[6];
    #pragma unroll
    for (int j = 0; j < 6; ++j) av[j] = a_vec[(wave * 6 + j) * 16 + lrow];

    const u16* bB = wfc + (wave * 96 + lrow) * 384 + quad * 8;

    int nidx[8], pidx[8], eidx[8];   // indices for NEXT tile's gathers

    int t = blockIdx.x;
    // ---- prologue: idx(t) -> issue GLD(t) -> idx(t+FCW_) ----
    #pragma unroll
    for (int rr = 0; rr < 8; ++rr) {
        const int m = t * 32 + wave * 8 + rr;
        nidx[rr] = starts[m]; pidx[rr] = paths[m]; eidx[rr] = ends[m];
    }
    #pragma unroll
    for (int rr = 0; rr < 8; ++rr) {
        const int r = wave * 8 + rr;
        const float* s01 = half ? (path_emb + (long)pidx[rr] * 128 + l32 * 4)
                                : (node_emb + (long)nidx[rr] * 128 + l32 * 4);
        GLD16(s01, &Af32[r * 388]);
        GLD4(node_emb + (long)eidx[rr] * 128 + lane,      &Af32[r * 388 + 256]);
        GLD4(node_emb + (long)eidx[rr] * 128 + 64 + lane, &Af32[r * 388 + 320]);
    }
    {
        const int tn = (t + FCW_ < NT_) ? (t + FCW_) : t;
        #pragma unroll
        for (int rr = 0; rr < 8; ++rr) {
            const int m = tn * 32 + wave * 8 + rr;
            nidx[rr] = starts[m]; pidx[rr] = paths[m]; eidx[rr] = ends[m];
        }
    }

    for (; t < NT_; t += FCW_) {
        // ---- gate: own-wave GLD(t) complete (wave staged its own 8 rows) ----
        VM_GATE();

        // ---- convert own 8 rows f32 -> bf16 (disjoint buffers, no overlay) ----
        {
            const int crow = wave * 8 + (lane >> 3);
            const int cb   = lane & 7;
            #pragma unroll
            for (int i = 0; i < 12; ++i) {
                const int c4 = cb + i * 8;            // 0..95
                float4 v = *(const float4*)&Af32[crow * 388 + c4 * 4];
                ushort4 o;
                o.x = f2bf(v.x); o.y = f2bf(v.y); o.z = f2bf(v.z); o.w = f2bf(v.w);
                *(ushort4*)&Ab16[crow * 392 + c4 * 4] = o;
            }
        }
        WG_BARRIER();   // all converts visible; f32stage free; vmcnt untouched

        // ---- issue GLD(t+1) into f32stage (flies across K-loop + epilogue) ----
        if (t + FCW_ < NT_) {
            #pragma unroll
            for (int rr = 0; rr < 8; ++rr) {
                const int r = wave * 8 + rr;
                const float* s01 = half ? (path_emb + (long)pidx[rr] * 128 + l32 * 4)
                                        : (node_emb + (long)nidx[rr] * 128 + l32 * 4);
                GLD16(s01, &Af32[r * 388]);
                GLD4(node_emb + (long)eidx[rr] * 128 + lane,      &Af32[r * 388 + 256]);
                GLD4(node_emb + (long)eidx[rr] * 128 + 64 + lane, &Af32[r * 388 + 320]);
            }
        }
        // ---- prefetch idx(t+2) into regs ----
        {
            int tnn = t + 2 * FCW_;
            tnn = (tnn < NT_) ? tnn : t;    // clamp keeps loads valid
            #pragma unroll
            for (int rr = 0; rr < 8; ++rr) {
                const int m = tnn * 32 + wave * 8 + rr;
                nidx[rr] = starts[m]; pidx[rr] = paths[m]; eidx[rr] = ends[m];
            }
        }

        // ---- MFMA K-loop (bf16 LDS A-frags + wfc B-frags from L1/L2) ----
        const u16* aB0 = Ab16 + lrow * 392 + quad * 8;
        const u16* aB1 = Ab16 + (16 + lrow) * 392 + quad * 8;
        f32x4 acc[2][6];
        #pragma unroll
        for (int mt = 0; mt < 2; ++mt)
            #pragma unroll
            for (int j = 0; j < 6; ++j) acc[mt][j] = (f32x4){0.f, 0.f, 0.f, 0.f};

        for (int kk = 0; kk < 12; ++kk) {
            bf16x8 a0 = *(const bf16x8*)(aB0 + kk * 32);
            bf16x8 a1 = *(const bf16x8*)(aB1 + kk * 32);
            #pragma unroll
            for (int j = 0; j < 6; ++j) {
                bf16x8 bfr = *(const bf16x8*)(bB + j * (16 * 384) + kk * 32);
                acc[0][j] = __builtin_amdgcn_mfma_f32_16x16x32_bf16(a0, bfr, acc[0][j], 0, 0, 0);
                acc[1][j] = __builtin_amdgcn_mfma_f32_16x16x32_bf16(a1, bfr, acc[1][j], 0, 0, 0);
            }
        }

        // ---- EP: tanh, h store, score partials (GLD(t+1) still flying) ----
        const int m0 = t * 32;
        float sc00 = 0.f, sc01 = 0.f, sc02 = 0.f, sc03 = 0.f;
        float sc10 = 0.f, sc11 = 0.f, sc12 = 0.f, sc13 = 0.f;
        #pragma unroll
        for (int j = 0; j < 6; ++j) {
            const int col = (wave * 6 + j) * 16 + lrow;
            const float avj = av[j];
            #pragma unroll
            for (int mt = 0; mt < 2; ++mt) {
                const int mrow = m0 + mt * 16 + quad * 4;
                #pragma unroll
                for (int rr = 0; rr < 4; ++rr) {
                    float pre = acc[mt][j][rr];
                    float e = __expf(2.0f * pre);
                    float hv = 1.0f - 2.0f / (e + 1.0f);
                    h_out[(long)(mrow + rr) * 384 + col] = f2bf(hv);
                    float hs = hv * avj;
                    if (mt == 0) {
                        if      (rr == 0) sc00 += hs; else if (rr == 1) sc01 += hs;
                        else if (rr == 2) sc02 += hs; else              sc03 += hs;
                    } else {
                        if      (rr == 0) sc10 += hs; else if (rr == 1) sc11 += hs;
                        else if (rr == 2) sc12 += hs; else              sc13 += hs;
                    }
                }
            }
        }
        #pragma unroll
        for (int off = 1; off < 16; off <<= 1) {
            sc00 += __shfl_xor(sc00, off); sc01 += __shfl_xor(sc01, off);
            sc02 += __shfl_xor(sc02, off); sc03 += __shfl_xor(sc03, off);
            sc10 += __shfl_xor(sc10, off); sc11 += __shfl_xor(sc11, off);
            sc12 += __shfl_xor(sc12, off); sc13 += __shfl_xor(sc13, off);
        }
        if (lrow == 0) {
            scpart[wave][quad * 4 + 0] = sc00;
            scpart[wave][quad * 4 + 1] = sc01;
            scpart[wave][quad * 4 + 2] = sc02;
            scpart[wave][quad * 4 + 3] = sc03;
            scpart[wave][16 + quad * 4 + 0] = sc10;
            scpart[wave][16 + quad * 4 + 1] = sc11;
            scpart[wave][16 + quad * 4 + 2] = sc12;
            scpart[wave][16 + quad * 4 + 3] = sc13;
        }
        WG_BARRIER();   // scpart visible; GLD(t+1) still in flight
        if (tid < 32)
            scores[m0 + tid] = scpart[0][tid] + scpart[1][tid] + scpart[2][tid] + scpart[3][tid];
    }
}

// ---------------- softmax over L=200 per batch row (1 wave/block) ----------------
__global__ void softmax_kernel(const float* __restrict__ scores, float* __restrict__ attn) {
    int b = blockIdx.x;
    int t = threadIdx.x;
    const float* s = scores + b * L_;
    float v0 = s[t];
    float v1 = s[t + 64];
    float v2 = s[t + 128];
    float v3 = (t < 8) ? s[t + 192] : -INFINITY;
    float mx = fmaxf(fmaxf(v0, v1), fmaxf(v2, v3));
    #pragma unroll
    for (int off = 1; off < 64; off <<= 1) mx = fmaxf(mx, __shfl_xor(mx, off));
    float e0 = __expf(v0 - mx), e1 = __expf(v1 - mx), e2 = __expf(v2 - mx);
    float e3 = (t < 8) ? __expf(v3 - mx) : 0.f;
    float sum = e0 + e1 + e2 + e3;
    #pragma unroll
    for (int off = 1; off < 64; off <<= 1) sum += __shfl_xor(sum, off);
    float inv = 1.f / sum;
    float* o = attn + b * L_;
    o[t] = e0 * inv; o[t + 64] = e1 * inv; o[t + 128] = e2 * inv;
    if (t < 8) o[t + 192] = e3 * inv;
}

// ---------------- code_vectors = sum_l attn * h (bf16x8 loads, 4-wave L split) ----
__global__ __launch_bounds__(256)
void codevec_kernel(const u16* __restrict__ h, const float* __restrict__ attn,
                    u16* __restrict__ cv) {
    __shared__ float part[4][384];
    const int b = blockIdx.x;
    const int tid = threadIdx.x, lane = tid & 63, wave = tid >> 6;
    float acc[8];
    #pragma unroll
    for (int e = 0; e < 8; ++e) acc[e] = 0.f;
    if (lane < 48) {
        const u16* hp = h + (long)b * (L_ * 384) + lane * 8;
        const float* ap = attn + b * L_;
        #pragma unroll 10
        for (int l = wave; l < L_; l += 4) {
            float w = ap[l];
            bf16x8 v = *(const bf16x8*)(hp + (long)l * 384);
            #pragma unroll
            for (int e = 0; e < 8; ++e) acc[e] += bf2f((u16)v[e]) * w;
        }
        #pragma unroll
        for (int e = 0; e < 8; ++e) part[wave][lane * 8 + e] = acc[e];
    }
    __syncthreads();
    for (int c = tid; c < 384; c += 256) {
        cv[b * 384 + c] = f2bf(part[0][c] + part[1][c] + part[2][c] + part[3][c]);
    }
}

// ---------------- out = cv @ W_out^T + b_out ----------------
__global__ __launch_bounds__(256, 4)
void out_gemm_kernel(const u16* __restrict__ cv, const u16* __restrict__ wout,
                     const float* __restrict__ b_out, float* __restrict__ out) {
    const int tid = threadIdx.x;
    const int lane = tid & 63, wave = tid >> 6;
    const int lrow = lane & 15, quad = lane >> 4;
    const int m0  = blockIdx.x * 64 + wave * 16;
    const int n0b = blockIdx.y * 128;

    f32x4 acc[8];
    #pragma unroll
    for (int i = 0; i < 8; ++i) acc[i] = (f32x4){0.f, 0.f, 0.f, 0.f};

    const u16* aB = cv + (m0 + lrow) * 384 + quad * 8;
    for (int kk = 0; kk < 12; ++kk) {
        bf16x8 af = *(const bf16x8*)(aB + kk * 32);
        #pragma unroll
        for (int t = 0; t < 8; ++t) {
            int n = n0b + t * 16 + lrow;
            n = (n < OUT_) ? n : (OUT_ - 1);
            bf16x8 bfr = *(const bf16x8*)(wout + (long)n * 384 + kk * 32 + quad * 8);
            acc[t] = __builtin_amdgcn_mfma_f32_16x16x32_bf16(af, bfr, acc[t], 0, 0, 0);
        }
    }
    const int mrow = m0 + quad * 4;
    #pragma unroll
    for (int t = 0; t < 8; ++t) {
        int n = n0b + t * 16 + lrow;
        if (n < OUT_) {
            float bias = b_out[n];
            #pragma unroll
            for (int r = 0; r < 4; ++r)
                out[(long)(mrow + r) * OUT_ + n] = acc[t][r] + bias;
        }
    }
}

extern "C" void kernel_launch(void* const* d_in, const int* in_sizes, int n_in,
                              void* d_out, int out_size, void* d_ws, size_t ws_size,
                              hipStream_t stream) {
    const int*   starts   = (const int*)d_in[0];
    const int*   paths    = (const int*)d_in[1];
    const int*   ends     = (const int*)d_in[2];
    const float* node_emb = (const float*)d_in[3];
    const float* path_emb = (const float*)d_in[4];
    const float* W_fc     = (const float*)d_in[5];
    const float* a_vec    = (const float*)d_in[6];
    const float* W_out    = (const float*)d_in[7];
    const float* b_out    = (const float*)d_in[8];
    float* out = (float*)d_out;

    char* ws = (char*)d_ws;
    u16*   h_bf16 = (u16*)ws;   ws += (size_t)M_ * 384 * 2;
    float* scores = (float*)ws; ws += (size_t)M_ * 4;
    float* attn   = (float*)ws; ws += (size_t)M_ * 4;
    u16*   wfc_b  = (u16*)ws;   ws += (size_t)C_ * K_ * 2;
    u16*   wout_b = (u16*)ws;   ws += (size_t)OUT_ * K_ * 2;
    u16*   cv_b   = (u16*)ws;   ws += (size_t)B_ * C_ * 2;

    cvt_bf16_kernel<<<(C_ * K_ / 4 + 255) / 256, 256, 0, stream>>>(
        (const float4*)W_fc, (ushort4*)wfc_b, C_ * K_ / 4);
    cvt_bf16_kernel<<<(OUT_ * K_ / 4 + 255) / 256, 256, 0, stream>>>(
        (const float4*)W_out, (ushort4*)wout_b, OUT_ * K_ / 4);
    fc_kernel<<<FCW_, 256, 0, stream>>>(
        starts, paths, ends, node_emb, path_emb, wfc_b, a_vec, h_bf16, scores);
    softmax_kernel<<<B_, 64, 0, stream>>>(scores, attn);
    codevec_kernel<<<B_, 256, 0, stream>>>(h_bf16, attn, cv_b);
    out_gemm_kernel<<<dim3(16, 79), 256, 0, stream>>>(cv_b, wout_b, b_out, out);
}